// Round 2
// baseline (268.496 us; speedup 1.0000x reference)
//
#include <hip/hip_runtime.h>
#include <hip/hip_bf16.h>

#define NND 300000
#define RR 1200
#define KADJ 20
#define BB 256
#define MM 50
#define DD 100
#define ROWS (BB*MM*KADJ)   // 256000
#define MKJ (MM*KADJ)       // 1000
#define N1P 208             // layer-1 out cols padded (2 heads x 100 -> 208 = 13 tiles)
#define N1T 13
#define N2T 7               // layer-2: 112 cols per head

typedef __attribute__((ext_vector_type(8))) short short8;
typedef __attribute__((ext_vector_type(4))) float f32x4;

__device__ inline unsigned short f2bf(float f) {
  union { float f; unsigned u; } v; v.f = f;
  unsigned r = (v.u + 0x7FFFu + ((v.u >> 16) & 1u)) >> 16;
  return (unsigned short)r;
}
__device__ inline float fast_tanh(float x) {
  float e = __expf(2.f * x);
  return 1.f - 2.f / (e + 1.f);
}

// ---------------- prep: weight fragments + G1/RL tables ----------------
__global__ __launch_bounds__(256) void k_prep(
    const float* __restrict__ gemb, const float* __restrict__ remb,
    const float* __restrict__ aw1, const float* __restrict__ ab1,
    const float* __restrict__ cw1, const float* __restrict__ cb1,
    const float* __restrict__ aw2, const float* __restrict__ cw2,
    short* __restrict__ wf1, short* __restrict__ wf2,
    float* __restrict__ G1, float* __restrict__ RL) {
  int t = blockIdx.x * blockDim.x + threadIdx.x;
  if (t < 26624) {  // wf1: 13nt*4ks*64lane*8
    int jj = t & 7, l = (t >> 3) & 63, f = t >> 9;
    int ks = f & 3, nt = f >> 2;
    int n = nt * 16 + (l & 15);
    int k = ks * 32 + ((l >> 4) * 8) + jj;
    float v = 0.f;
    if (k < DD && n < 200) {
      const float* w1 = (n < DD) ? aw1 : cw1;
      int j = (n < DD) ? n : n - DD;
      v = w1[(DD + k) * DD + j];
    }
    wf1[t] = (short)f2bf(v);
    return;
  }
  int t2 = t - 26624;
  if (t2 < 28672) {  // wf2: 2h * 7nt*4ks*64*8
    int h = t2 / 14336; int s = t2 % 14336;
    int jj = s & 7, l = (s >> 3) & 63, f = s >> 9;
    int ks = f & 3, nt = f >> 2;
    int n = nt * 16 + (l & 15);
    int k = ks * 32 + ((l >> 4) * 8) + jj;
    float v = 0.f;
    const float* w2 = h ? cw2 : aw2;
    if (k < DD && n < DD) v = w2[k * DD + n];
    wf2[t2] = (short)f2bf(v);
    return;
  }
  int t3 = t2 - 28672;
  if (t3 < BB * N1P) {
    int b = t3 / N1P, n = t3 % N1P;
    float acc = 0.f;
    if (n < 200) {
      const float* w1 = (n < DD) ? aw1 : cw1;
      const float* b1 = (n < DD) ? ab1 : cb1;
      int j = (n < DD) ? n : n - DD;
      acc = b1[j];
      for (int d = 0; d < DD; ++d) acc += gemb[b * DD + d] * w1[d * DD + j];
    }
    G1[t3] = acc;
    return;
  }
  int t4 = t3 - BB * N1P;
  if (t4 < RR * N1P) {
    int rid = t4 / N1P, n = t4 % N1P;
    float acc = 0.f;
    if (n < 200) {
      const float* w1 = (n < DD) ? aw1 : cw1;
      int j = (n < DD) ? n : n - DD;
      for (int d = 0; d < DD; ++d) acc += remb[rid * DD + d] * w1[(200 + d) * DD + j];
    }
    RL[t4] = acc;
  }
}

// ---------------- heads: per-row 2-head MLP via MFMA ----------------
__global__ __launch_bounds__(256) void k_heads(
    const float* __restrict__ nemb,
    const int* __restrict__ eadj, const int* __restrict__ radj,
    const int* __restrict__ nodes,
    const short* __restrict__ wf1, const short* __restrict__ wf2,
    const float* __restrict__ G1, const float* __restrict__ RL,
    const float* __restrict__ ab2, const float* __restrict__ cb2,
    const float* __restrict__ aw3, const float* __restrict__ ab3,
    const float* __restrict__ cw3, const float* __restrict__ cb3,
    float* __restrict__ outA, float* __restrict__ outQ) {
  __shared__ unsigned short X[64 * 128];        // node rows, bf16, XOR-swizzled
  __shared__ unsigned short H1[2 * 64 * 128];   // tanh(layer1) per head, bf16, swizzled
  __shared__ int nidA[64], ridA[64], biA[64];

  int tid = threadIdx.x;
  int row0 = blockIdx.x * 64;

  // phase 0: row indices
  if (tid < 64) {
    int row = row0 + tid;
    int b = row / MKJ;
    int rem = row - b * MKJ;
    int m = rem / KADJ, kk = rem - m * KADJ;
    int v = nodes[b * MM + m];
    nidA[tid] = eadj[v * KADJ + kk];
    ridA[tid] = radj[v * KADJ + kk];
    biA[tid] = b;
  }
  __syncthreads();

  // phase 1: stage node rows -> bf16 LDS (pad cols 100..127 = 0)
  {
    int rr = tid >> 2, sub = tid & 3;
    int nid = nidA[rr];
    const float* src = nemb + (long long)nid * DD;
    #pragma unroll
    for (int it = 0; it < 8; ++it) {
      int idx = sub + it * 4;           // 0..31
      int col = idx * 4;
      float4 v = make_float4(0.f, 0.f, 0.f, 0.f);
      if (col < DD) v = *(const float4*)(src + col);
      int pc = col ^ ((rr & 7) << 3);
      unsigned long long pack = (unsigned long long)f2bf(v.x) |
                                ((unsigned long long)f2bf(v.y) << 16) |
                                ((unsigned long long)f2bf(v.z) << 32) |
                                ((unsigned long long)f2bf(v.w) << 48);
      *(unsigned long long*)(X + rr * 128 + pc) = pack;
    }
  }
  __syncthreads();

  int lane = tid & 63;
  int w = tid >> 6;       // wave 0..3 -> m-tile
  int lg = lane >> 4;     // lane group
  int ln = lane & 15;

  int b_[4], rid_[4];
  #pragma unroll
  for (int r = 0; r < 4; ++r) {
    int rl = w * 16 + lg * 4 + r;
    b_[r] = biA[rl];
    rid_[r] = ridA[rl];
  }

  // layer-1 A fragments
  short8 a1[4];
  {
    int row = w * 16 + ln;
    int swz = (row & 7) << 3;
    #pragma unroll
    for (int ks = 0; ks < 4; ++ks) {
      int col = (ks * 32 + lg * 8) ^ swz;
      a1[ks] = *(const short8*)(X + row * 128 + col);
    }
  }

  const short8* WF1 = (const short8*)wf1;
  for (int nt = 0; nt < N1T; ++nt) {
    f32x4 acc = {0.f, 0.f, 0.f, 0.f};
    #pragma unroll
    for (int ks = 0; ks < 4; ++ks) {
      short8 bf = WF1[(nt * 4 + ks) * 64 + lane];
      acc = __builtin_amdgcn_mfma_f32_16x16x32_bf16(a1[ks], bf, acc, 0, 0, 0);
    }
    int n = nt * 16 + ln;
    if (n < 200) {
      int h = (n >= DD) ? 1 : 0;
      int j = h ? n - DD : n;
      unsigned short* H1h = H1 + h * 8192;
      #pragma unroll
      for (int r = 0; r < 4; ++r) {
        float pre = acc[r] + G1[b_[r] * N1P + n] + RL[rid_[r] * N1P + n];
        int rl = w * 16 + lg * 4 + r;
        H1h[rl * 128 + (j ^ ((rl & 7) << 3))] = f2bf(fast_tanh(pre));
      }
    }
  }
  // zero K-pad cols 100..127 of own wave's H1 rows (both heads)
  for (int i = lane; i < 16 * 28 * 2; i += 64) {
    int h = i / (16 * 28); int s = i % (16 * 28);
    int rl = w * 16 + s / 28; int c = 100 + s % 28;
    H1[h * 8192 + rl * 128 + (c ^ ((rl & 7) << 3))] = 0;
  }
  __syncthreads();

  // layer-2 + layer-3 per head
  const float* b2p[2] = {ab2, cb2};
  const float* w3p[2] = {aw3, cw3};
  float b3v[2] = {ab3[0], cb3[0]};
  float res[2][4];
  #pragma unroll
  for (int h = 0; h < 2; ++h) {
    const unsigned short* H1h = H1 + h * 8192;
    short8 a2[4];
    {
      int row = w * 16 + ln;
      int swz = (row & 7) << 3;
      #pragma unroll
      for (int ks = 0; ks < 4; ++ks) {
        int col = (ks * 32 + lg * 8) ^ swz;
        a2[ks] = *(const short8*)(H1h + row * 128 + col);
      }
    }
    const short8* WF2 = (const short8*)(wf2 + h * 14336);
    float part[4] = {0.f, 0.f, 0.f, 0.f};
    for (int nt = 0; nt < N2T; ++nt) {
      f32x4 acc = {0.f, 0.f, 0.f, 0.f};
      #pragma unroll
      for (int ks = 0; ks < 4; ++ks) {
        short8 bf = WF2[(nt * 4 + ks) * 64 + lane];
        acc = __builtin_amdgcn_mfma_f32_16x16x32_bf16(a2[ks], bf, acc, 0, 0, 0);
      }
      int n = nt * 16 + ln;
      float b2v = (n < DD) ? b2p[h][n] : 0.f;
      float w3v = (n < DD) ? w3p[h][n] : 0.f;
      #pragma unroll
      for (int r = 0; r < 4; ++r) {
        float h2 = fast_tanh(acc[r] + b2v);
        part[r] += h2 * w3v;
      }
    }
    #pragma unroll
    for (int r = 0; r < 4; ++r) {
      float s = part[r];
      s += __shfl_xor(s, 1, 64); s += __shfl_xor(s, 2, 64);
      s += __shfl_xor(s, 4, 64); s += __shfl_xor(s, 8, 64);
      res[h][r] = s;
    }
  }
  if (ln == 0) {
    float* outs[2] = {outA, outQ};
    #pragma unroll
    for (int h = 0; h < 2; ++h)
      #pragma unroll
      for (int r = 0; r < 4; ++r) {
        int rl = w * 16 + lg * 4 + r;
        outs[h][row0 + rl] = 1.f / (1.f + __expf(-(res[h][r] + b3v[h])));
      }
  }
}

// ---------------- rewards: dots + softmax + new_graph_embedding ----------------
__global__ __launch_bounds__(512) void k_rewards(
    const float* __restrict__ nemb, const float* __restrict__ oemb,
    const float* __restrict__ gemb,
    const int* __restrict__ eadj, const int* __restrict__ nodes,
    float* __restrict__ outDR, float* __restrict__ outNG) {
  __shared__ float dots[MKJ];
  __shared__ float red[8];
  int b = blockIdx.x;
  int tid = threadIdx.x;
  int lane = tid & 63, w = tid >> 6;
  int d1 = lane + 64;
  float o0 = oemb[b * DD + lane];
  float g0 = gemb[b * DD + lane];
  float o1 = (d1 < DD) ? oemb[b * DD + d1] : 0.f;
  float g1 = (d1 < DD) ? gemb[b * DD + d1] : 0.f;
  for (int j = w; j < MKJ; j += 8) {
    int m = j / KADJ, kk = j - m * KADJ;
    int v = nodes[b * MM + m];
    int nid = eadj[v * KADJ + kk];
    const float* nr = nemb + (long long)nid * DD;
    float s0 = g0 + nr[lane];
    float s1 = (d1 < DD) ? (g1 + nr[d1]) : 0.f;
    float* ngr = outNG + ((long long)b * MKJ + j) * DD;
    ngr[lane] = s0;
    if (d1 < DD) ngr[d1] = s1;
    float p = o0 * s0 + o1 * s1;
    p += __shfl_xor(p, 1, 64); p += __shfl_xor(p, 2, 64); p += __shfl_xor(p, 4, 64);
    p += __shfl_xor(p, 8, 64); p += __shfl_xor(p, 16, 64); p += __shfl_xor(p, 32, 64);
    if (lane == 0) dots[j] = p;
  }
  __syncthreads();
  float mx = -1e30f;
  for (int j = tid; j < MKJ; j += 512) mx = fmaxf(mx, dots[j]);
  for (int off = 32; off; off >>= 1) mx = fmaxf(mx, __shfl_xor(mx, off, 64));
  if (lane == 0) red[w] = mx;
  __syncthreads();
  mx = red[0];
  #pragma unroll
  for (int i = 1; i < 8; ++i) mx = fmaxf(mx, red[i]);
  float se = 0.f;
  for (int j = tid; j < MKJ; j += 512) se += __expf(dots[j] - mx);
  for (int off = 32; off; off >>= 1) se += __shfl_xor(se, off, 64);
  __syncthreads();
  if (lane == 0) red[w] = se;
  __syncthreads();
  se = 0.f;
  #pragma unroll
  for (int i = 0; i < 8; ++i) se += red[i];
  float inv = 1.f / se;
  for (int j = tid; j < MKJ; j += 512) outDR[b * MKJ + j] = __expf(dots[j] - mx) * inv;
}

extern "C" void kernel_launch(void* const* d_in, const int* in_sizes, int n_in,
                              void* d_out, int out_size, void* d_ws, size_t ws_size,
                              hipStream_t stream) {
  const float* nemb = (const float*)d_in[0];
  const float* remb = (const float*)d_in[1];
  const float* oemb = (const float*)d_in[2];
  const float* gemb = (const float*)d_in[3];
  const float* aw1 = (const float*)d_in[4];
  const float* ab1 = (const float*)d_in[5];
  const float* aw2 = (const float*)d_in[6];
  const float* ab2 = (const float*)d_in[7];
  const float* aw3 = (const float*)d_in[8];
  const float* ab3 = (const float*)d_in[9];
  const float* cw1 = (const float*)d_in[10];
  const float* cb1 = (const float*)d_in[11];
  const float* cw2 = (const float*)d_in[12];
  const float* cb2 = (const float*)d_in[13];
  const float* cw3 = (const float*)d_in[14];
  const float* cb3 = (const float*)d_in[15];
  const int* eadj = (const int*)d_in[16];
  const int* radj = (const int*)d_in[17];
  const int* nodes = (const int*)d_in[18];

  float* out = (float*)d_out;
  float* outA = out;
  float* outQ = out + ROWS;
  float* outDR = out + 2 * ROWS;
  float* outNG = out + 3 * ROWS;

  // scratch layout: wf1(53248 B) | wf2(57344 B) | G1(212992 B) | RL(998400 B)
  const size_t need = 1321984;
  char* scratch = (char*)d_ws;
  if (ws_size < need) {
    // fall back to the tail of the nge output region; k_rewards overwrites it after k_heads reads
    scratch = (char*)(out + ((size_t)3 * ROWS + (size_t)ROWS * DD - need / 4));
  }
  short* wf1 = (short*)scratch;
  short* wf2 = (short*)(scratch + 53248);
  float* G1 = (float*)(scratch + 110592);
  float* RL = (float*)(scratch + 323584);

  k_prep<<<1399, 256, 0, stream>>>(gemb, remb, aw1, ab1, cw1, cb1, aw2, cw2,
                                   wf1, wf2, G1, RL);
  k_heads<<<ROWS / 64, 256, 0, stream>>>(nemb, eadj, radj, nodes, wf1, wf2, G1, RL,
                                         ab2, cb2, aw3, ab3, cw3, cb3, outA, outQ);
  k_rewards<<<BB, 512, 0, stream>>>(nemb, oemb, gemb, eadj, nodes, outDR, outNG);
}

// Round 3
// 223.659 us; speedup vs baseline: 1.2005x; 1.2005x over previous
//
#include <hip/hip_runtime.h>
#include <hip/hip_bf16.h>

#define NND 300000
#define RR 1200
#define KADJ 20
#define BB 256
#define MM 50
#define DD 100
#define ROWS (BB*MM*KADJ)   // 256000
#define MKJ (MM*KADJ)       // 1000
#define N1P 208             // G1 table row length (actor 0..99, critic 100..199)
#define K1S 8               // layer-1 packed K = 256 -> 8 ks steps
#define NT1 7               // per-head N tiles (112 cols, 100 valid)
#define NT2 7
#define K2S 4               // layer-2 K = 128 -> 4 ks steps
#define H1S 136             // H1 LDS row stride (shorts); 68 dwords % 32 = 4 -> ~2-way

typedef __attribute__((ext_vector_type(8))) short short8;
typedef __attribute__((ext_vector_type(4))) float f32x4;

__device__ inline unsigned short f2bf(float f) {
  union { float f; unsigned u; } v; v.f = f;
  return (unsigned short)((v.u + 0x7FFFu + ((v.u >> 16) & 1u)) >> 16);
}
__device__ inline unsigned pkbf2(float x, float y) {
  __hip_bfloat162 p = __float22bfloat162_rn(make_float2(x, y));
  unsigned u; __builtin_memcpy(&u, &p, 4); return u;
}
__device__ inline float fast_tanh(float x) {
  float e = __builtin_amdgcn_exp2f(x * 2.885390082f);   // e^{2x}
  float r = __builtin_amdgcn_rcpf(e + 1.f);
  return __builtin_fmaf(-2.f, r, 1.f);
}
__device__ inline float fast_sigmoid(float x) {
  float e = __builtin_amdgcn_exp2f(x * -1.442695041f);  // e^{-x}
  return __builtin_amdgcn_rcpf(1.f + e);
}

// ---------------- prep: packed weight fragments + G1 table ----------------
// wf1[h][nt][ks][lane][j]: packed-K layer1 weights. kp<100 -> w1 row 100+kp (node),
//   128<=kp<228 -> w1 row 200+(kp-128) (rel), else 0. n = nt*16+(lane&15) (<100 valid).
// wf2[h][nt][ks][lane][j]: layer2, k<100 valid.
// G1[b][n] (n<100 actor+b1, 100..199 critic+b1)
__global__ __launch_bounds__(256) void k_prep(
    const float* __restrict__ gemb,
    const float* __restrict__ aw1, const float* __restrict__ ab1,
    const float* __restrict__ cw1, const float* __restrict__ cb1,
    const float* __restrict__ aw2, const float* __restrict__ cw2,
    short* __restrict__ wf1, short* __restrict__ wf2, float* __restrict__ G1) {
  int t = blockIdx.x * blockDim.x + threadIdx.x;
  if (t < 57344) {  // wf1: 2h * 7nt * 8ks * 64 * 8
    int j = t & 7, l = (t >> 3) & 63, f = t >> 9;
    int ks = f & 7, r2 = f >> 3;
    int nt = r2 % 7, h = r2 / 7;
    int kp = ks * 32 + ((l >> 4) * 8) + j;
    int n = nt * 16 + (l & 15);
    float v = 0.f;
    if (n < DD) {
      const float* w1 = h ? cw1 : aw1;
      if (kp < DD) v = w1[(DD + kp) * DD + n];
      else if (kp >= 128 && kp < 228) v = w1[(200 + kp - 128) * DD + n];
    }
    wf1[t] = (short)f2bf(v);
    return;
  }
  int t2 = t - 57344;
  if (t2 < 28672) {  // wf2: 2h * 7nt * 4ks * 64 * 8
    int j = t2 & 7, l = (t2 >> 3) & 63, f = t2 >> 9;
    int ks = f & 3, r2 = f >> 2;
    int nt = r2 % 7, h = r2 / 7;
    int k = ks * 32 + ((l >> 4) * 8) + j;
    int n = nt * 16 + (l & 15);
    float v = 0.f;
    if (k < DD && n < DD) v = (h ? cw2 : aw2)[k * DD + n];
    wf2[t2] = (short)f2bf(v);
    return;
  }
  int t3 = t2 - 28672;
  if (t3 < BB * N1P) {  // G1
    int b = t3 / N1P, n = t3 % N1P;
    float acc = 0.f;
    if (n < 200) {
      const float* w1 = (n < DD) ? aw1 : cw1;
      const float* b1 = (n < DD) ? ab1 : cb1;
      int jj = (n < DD) ? n : n - DD;
      acc = b1[jj];
      for (int d = 0; d < DD; ++d) acc += gemb[b * DD + d] * w1[d * DD + jj];
    }
    G1[t3] = acc;
  }
}

// ---------------- heads: per-row 2-head MLP, fragments direct from global ----------------
__global__ __launch_bounds__(256, 4) void k_heads(
    const float* __restrict__ nemb, const float* __restrict__ remb,
    const int* __restrict__ eadj, const int* __restrict__ radj,
    const int* __restrict__ nodes,
    const short* __restrict__ wf1, const short* __restrict__ wf2,
    const float* __restrict__ G1,
    const float* __restrict__ ab2, const float* __restrict__ cb2,
    const float* __restrict__ aw3, const float* __restrict__ ab3,
    const float* __restrict__ cw3, const float* __restrict__ cb3,
    float* __restrict__ outA, float* __restrict__ outQ) {
  __shared__ unsigned short H1[64 * H1S];   // 17,408 B, per-wave-private 16-row slabs
  __shared__ float G1s[224], b2s[224], w3s[224];
  __shared__ int nidA[64], ridA[64];

  int b = blockIdx.y;
  int x = blockIdx.x;        // row tile within b (16 tiles of 64; tile 15 has 40 valid)
  int tid = threadIdx.x;

  for (int i = tid; i < 224; i += 256) {
    int h = i / 112, n = i - h * 112;
    G1s[i] = (n < DD) ? G1[b * N1P + h * DD + n] : 0.f;
    b2s[i] = (n < DD) ? (h ? cb2[n] : ab2[n]) : 0.f;
    w3s[i] = (n < DD) ? (h ? cw3[n] : aw3[n]) : 0.f;
  }
  if (tid < 64) {
    int row = x * 64 + tid; if (row > MKJ - 1) row = MKJ - 1;
    int m = row / KADJ, kk = row - m * KADJ;
    int v = nodes[b * MM + m];
    nidA[tid] = eadj[v * KADJ + kk];
    ridA[tid] = radj[v * KADJ + kk];
  }
  for (int i = tid; i < 64 * H1S / 8; i += 256)
    ((uint4*)H1)[i] = make_uint4(0, 0, 0, 0);
  __syncthreads();

  int lane = tid & 63, w = tid >> 6;
  int ln = lane & 15, lg = lane >> 4;
  int myrow = w * 16 + ln;   // A-row this lane serves
  const float* nrow = nemb + (size_t)nidA[myrow] * DD;
  const float* rrow = remb + (size_t)ridA[myrow] * DD;

  // build layer-1 A fragments directly from global (packed K=256)
  short8 a1[8];
  #pragma unroll
  for (int ks = 0; ks < 8; ++ks) {
    const float* src = (ks < 4) ? nrow : rrow;
    int cb = (ks & 3) * 32 + lg * 8;
    float4 lo = make_float4(0.f, 0.f, 0.f, 0.f), hi = lo;
    if (cb <= 96) lo = *(const float4*)(src + cb);
    if (cb + 4 <= 96) hi = *(const float4*)(src + cb + 4);
    union { short8 s; unsigned u[4]; } fr;
    fr.u[0] = pkbf2(lo.x, lo.y); fr.u[1] = pkbf2(lo.z, lo.w);
    fr.u[2] = pkbf2(hi.x, hi.y); fr.u[3] = pkbf2(hi.z, hi.w);
    a1[ks] = fr.s;
  }

  float b3v[2] = {ab3[0], cb3[0]};
  float* outs[2] = {outA, outQ};

  for (int h = 0; h < 2; ++h) {
    // ---- layer 1: acc init = G1 (C-operand), 8 ks MFMA, tanh -> H1 ----
    const short8* WF1h = (const short8*)wf1 + (size_t)h * (NT1 * K1S * 64);
    for (int nt = 0; nt < NT1; ++nt) {
      int n = nt * 16 + ln;
      float g = G1s[h * 112 + n];
      f32x4 acc = {g, g, g, g};
      #pragma unroll
      for (int ks = 0; ks < K1S; ++ks)
        acc = __builtin_amdgcn_mfma_f32_16x16x32_bf16(a1[ks], WF1h[(nt * K1S + ks) * 64 + lane], acc, 0, 0, 0);
      if (n < DD) {
        #pragma unroll
        for (int r = 0; r < 4; ++r) {
          int rl = w * 16 + lg * 4 + r;
          H1[rl * H1S + n] = f2bf(fast_tanh(acc[r]));
        }
      }
    }
    __syncthreads();

    // ---- layer 2 + 3 ----
    short8 a2[4];
    #pragma unroll
    for (int ks = 0; ks < K2S; ++ks)
      a2[ks] = *(const short8*)(H1 + myrow * H1S + ks * 32 + lg * 8);

    const short8* WF2h = (const short8*)wf2 + (size_t)h * (NT2 * K2S * 64);
    float part[4] = {0.f, 0.f, 0.f, 0.f};
    for (int nt = 0; nt < NT2; ++nt) {
      f32x4 acc = {0.f, 0.f, 0.f, 0.f};
      #pragma unroll
      for (int ks = 0; ks < K2S; ++ks)
        acc = __builtin_amdgcn_mfma_f32_16x16x32_bf16(a2[ks], WF2h[(nt * K2S + ks) * 64 + lane], acc, 0, 0, 0);
      int n = nt * 16 + ln;
      float b2v = b2s[h * 112 + n];
      float w3v = w3s[h * 112 + n];
      #pragma unroll
      for (int r = 0; r < 4; ++r)
        part[r] += fast_tanh(acc[r] + b2v) * w3v;
    }
    #pragma unroll
    for (int r = 0; r < 4; ++r) {
      float s = part[r];
      s += __shfl_xor(s, 1, 64); s += __shfl_xor(s, 2, 64);
      s += __shfl_xor(s, 4, 64); s += __shfl_xor(s, 8, 64);
      if (ln == 0) {
        int rl = w * 16 + lg * 4 + r;
        int row = x * 64 + rl;
        if (row < MKJ) outs[h][b * MKJ + row] = fast_sigmoid(s + b3v[h]);
      }
    }
    __syncthreads();   // before next head overwrites H1
  }
}

// ---------------- rewards: dots + softmax + new_graph_embedding ----------------
__global__ __launch_bounds__(1024) void k_rewards(
    const float* __restrict__ nemb, const float* __restrict__ oemb,
    const float* __restrict__ gemb,
    const int* __restrict__ eadj, const int* __restrict__ nodes,
    float* __restrict__ outDR, float* __restrict__ outNG) {
  __shared__ float dots[MKJ];
  __shared__ float red[16];
  int b = blockIdx.x;
  int tid = threadIdx.x;
  int lane = tid & 63, w = tid >> 6;   // 16 waves
  int d1 = lane + 64;
  float o0 = oemb[b * DD + lane];
  float g0 = gemb[b * DD + lane];
  float o1 = (d1 < DD) ? oemb[b * DD + d1] : 0.f;
  float g1 = (d1 < DD) ? gemb[b * DD + d1] : 0.f;
  for (int j = w; j < MKJ; j += 16) {
    int m = j / KADJ, kk = j - m * KADJ;
    int v = nodes[b * MM + m];
    int nid = eadj[v * KADJ + kk];
    const float* nr = nemb + (size_t)nid * DD;
    float s0 = g0 + nr[lane];
    float s1 = (d1 < DD) ? (g1 + nr[d1]) : 0.f;
    float* ngr = outNG + ((long long)b * MKJ + j) * DD;
    ngr[lane] = s0;
    if (d1 < DD) ngr[d1] = s1;
    float p = o0 * s0 + o1 * s1;
    p += __shfl_xor(p, 1, 64); p += __shfl_xor(p, 2, 64); p += __shfl_xor(p, 4, 64);
    p += __shfl_xor(p, 8, 64); p += __shfl_xor(p, 16, 64); p += __shfl_xor(p, 32, 64);
    if (lane == 0) dots[j] = p;
  }
  __syncthreads();
  float mx = -1e30f;
  for (int j = tid; j < MKJ; j += 1024) mx = fmaxf(mx, dots[j]);
  for (int off = 32; off; off >>= 1) mx = fmaxf(mx, __shfl_xor(mx, off, 64));
  if (lane == 0) red[w] = mx;
  __syncthreads();
  mx = red[0];
  #pragma unroll
  for (int i = 1; i < 16; ++i) mx = fmaxf(mx, red[i]);
  float se = 0.f;
  for (int j = tid; j < MKJ; j += 1024) se += __expf(dots[j] - mx);
  for (int off = 32; off; off >>= 1) se += __shfl_xor(se, off, 64);
  __syncthreads();
  if (lane == 0) red[w] = se;
  __syncthreads();
  se = 0.f;
  #pragma unroll
  for (int i = 0; i < 16; ++i) se += red[i];
  float inv = 1.f / se;
  for (int j = tid; j < MKJ; j += 1024) outDR[b * MKJ + j] = __expf(dots[j] - mx) * inv;
}

extern "C" void kernel_launch(void* const* d_in, const int* in_sizes, int n_in,
                              void* d_out, int out_size, void* d_ws, size_t ws_size,
                              hipStream_t stream) {
  const float* nemb = (const float*)d_in[0];
  const float* remb = (const float*)d_in[1];
  const float* oemb = (const float*)d_in[2];
  const float* gemb = (const float*)d_in[3];
  const float* aw1 = (const float*)d_in[4];
  const float* ab1 = (const float*)d_in[5];
  const float* aw2 = (const float*)d_in[6];
  const float* ab2 = (const float*)d_in[7];
  const float* aw3 = (const float*)d_in[8];
  const float* ab3 = (const float*)d_in[9];
  const float* cw1 = (const float*)d_in[10];
  const float* cb1 = (const float*)d_in[11];
  const float* cw2 = (const float*)d_in[12];
  const float* cb2 = (const float*)d_in[13];
  const float* cw3 = (const float*)d_in[14];
  const float* cb3 = (const float*)d_in[15];
  const int* eadj = (const int*)d_in[16];
  const int* radj = (const int*)d_in[17];
  const int* nodes = (const int*)d_in[18];

  float* out = (float*)d_out;
  float* outA = out;
  float* outQ = out + ROWS;
  float* outDR = out + 2 * ROWS;
  float* outNG = out + 3 * ROWS;

  // scratch: wf1 114,688 B | wf2 57,344 B | G1 212,992 B = 385,024 B
  const size_t need = 385024;
  char* scratch = (char*)d_ws;
  if (ws_size < need) {
    // fallback: tail of outNG region (read by k_heads, then overwritten by k_rewards)
    scratch = (char*)(out + ((size_t)3 * ROWS + (size_t)ROWS * DD - need / 4));
  }
  short* wf1 = (short*)scratch;
  short* wf2 = (short*)(scratch + 114688);
  float* G1 = (float*)(scratch + 172032);

  k_prep<<<544, 256, 0, stream>>>(gemb, aw1, ab1, cw1, cb1, aw2, cw2, wf1, wf2, G1);
  dim3 hg(16, BB);
  k_heads<<<hg, 256, 0, stream>>>(nemb, remb, eadj, radj, nodes, wf1, wf2, G1,
                                  ab2, cb2, aw3, ab3, cw3, cb3, outA, outQ);
  k_rewards<<<BB, 1024, 0, stream>>>(nemb, oemb, gemb, eadj, nodes, outDR, outNG);
}

// Round 4
// 185.450 us; speedup vs baseline: 1.4478x; 1.2060x over previous
//
#include <hip/hip_runtime.h>
#include <hip/hip_bf16.h>

#define NND 300000
#define RR 1200
#define KADJ 20
#define BB 256
#define MM 50
#define DD 100
#define ROWS (BB*MM*KADJ)   // 256000
#define MKJ (MM*KADJ)       // 1000
#define N1P 208
#define K1S 8               // layer-1 packed K = 256 -> 8 ks steps
#define NT1 7
#define NT2 7
#define K2S 4
#define H1S 136             // H1 row stride in shorts

typedef __attribute__((ext_vector_type(8))) short short8;
typedef __attribute__((ext_vector_type(4))) float f32x4;

__device__ inline unsigned short f2bf(float f) {
  union { float f; unsigned u; } v; v.f = f;
  return (unsigned short)((v.u + 0x7FFFu + ((v.u >> 16) & 1u)) >> 16);
}
__device__ inline unsigned pkbf2(float x, float y) {
  __hip_bfloat162 p = __float22bfloat162_rn(make_float2(x, y));
  unsigned u; __builtin_memcpy(&u, &p, 4); return u;
}
__device__ inline float fast_tanh(float x) {
  float e = __builtin_amdgcn_exp2f(x * 2.885390082f);
  float r = __builtin_amdgcn_rcpf(e + 1.f);
  return __builtin_fmaf(-2.f, r, 1.f);
}
__device__ inline float fast_sigmoid(float x) {
  float e = __builtin_amdgcn_exp2f(x * -1.442695041f);
  return __builtin_amdgcn_rcpf(1.f + e);
}

// ---------------- prep: packed weight fragments + G1 table ----------------
__global__ __launch_bounds__(256) void k_prep(
    const float* __restrict__ gemb,
    const float* __restrict__ aw1, const float* __restrict__ ab1,
    const float* __restrict__ cw1, const float* __restrict__ cb1,
    const float* __restrict__ aw2, const float* __restrict__ cw2,
    short* __restrict__ wf1, short* __restrict__ wf2, float* __restrict__ G1) {
  int t = blockIdx.x * blockDim.x + threadIdx.x;
  if (t < 57344) {  // wf1: 2h*7nt*8ks*64*8
    int j = t & 7, l = (t >> 3) & 63, f = t >> 9;
    int ks = f & 7, r2 = f >> 3;
    int nt = r2 % 7, h = r2 / 7;
    int kp = ks * 32 + ((l >> 4) * 8) + j;
    int n = nt * 16 + (l & 15);
    float v = 0.f;
    if (n < DD) {
      const float* w1 = h ? cw1 : aw1;
      if (kp < DD) v = w1[(DD + kp) * DD + n];
      else if (kp >= 128 && kp < 228) v = w1[(200 + kp - 128) * DD + n];
    }
    wf1[t] = (short)f2bf(v);
    return;
  }
  int t2 = t - 57344;
  if (t2 < 28672) {  // wf2
    int j = t2 & 7, l = (t2 >> 3) & 63, f = t2 >> 9;
    int ks = f & 3, r2 = f >> 2;
    int nt = r2 % 7, h = r2 / 7;
    int k = ks * 32 + ((l >> 4) * 8) + j;
    int n = nt * 16 + (l & 15);
    float v = 0.f;
    if (k < DD && n < DD) v = (h ? cw2 : aw2)[k * DD + n];
    wf2[t2] = (short)f2bf(v);
    return;
  }
  int t3 = t2 - 28672;
  if (t3 < BB * N1P) {  // G1
    int b = t3 / N1P, n = t3 % N1P;
    float acc = 0.f;
    if (n < 200) {
      const float* w1 = (n < DD) ? aw1 : cw1;
      const float* b1 = (n < DD) ? ab1 : cb1;
      int jj = (n < DD) ? n : n - DD;
      acc = b1[jj];
      for (int d = 0; d < DD; ++d) acc += gemb[b * DD + d] * w1[d * DD + jj];
    }
    G1[t3] = acc;
  }
}

// ---------------- heads: 256 rows/block, 4 m-tiles per wave ----------------
template<bool FUSE>
__global__ __launch_bounds__(256, 2) void k_heads(
    const float* __restrict__ nemb, const float* __restrict__ remb,
    const float* __restrict__ oemb, const float* __restrict__ gemb,
    const int* __restrict__ eadj, const int* __restrict__ radj,
    const int* __restrict__ nodes,
    const short* __restrict__ wf1, const short* __restrict__ wf2,
    const float* __restrict__ G1,
    const float* __restrict__ ab2, const float* __restrict__ cb2,
    const float* __restrict__ aw3, const float* __restrict__ ab3,
    const float* __restrict__ cw3, const float* __restrict__ cb3,
    float* __restrict__ outA, float* __restrict__ outQ,
    float* __restrict__ dots, float* __restrict__ outNG) {
  __shared__ unsigned short H1[256 * H1S];       // 69,632 B (wave-private 64-row slabs)
  __shared__ float G1s[224], b2s[224], w3s[224];
  __shared__ float gs[112], os[112];

  int b = blockIdx.y, x = blockIdx.x, tid = threadIdx.x;
  int lane = tid & 63, w = tid >> 6, ln = lane & 15, lg = lane >> 4;

  // per-lane index chains (issue early)
  int rowL[4], nid[4], rid[4];
  #pragma unroll
  for (int mt = 0; mt < 4; ++mt) {
    int row = x * 256 + w * 64 + mt * 16 + ln;
    rowL[mt] = row;
    int rc = row < MKJ ? row : MKJ - 1;
    int m = rc / KADJ, kk = rc - m * KADJ;
    int v = nodes[b * MM + m];
    nid[mt] = eadj[v * KADJ + kk];
    rid[mt] = radj[v * KADJ + kk];
  }

  // table staging + H1 pad-zeroing
  for (int i = tid; i < 224; i += 256) {
    int h = i / 112, n = i - h * 112;
    G1s[i] = (n < DD) ? G1[b * N1P + h * DD + n] : 0.f;
    b2s[i] = (n < DD) ? (h ? cb2[n] : ab2[n]) : 0.f;
    w3s[i] = (n < DD) ? (h ? cw3[n] : aw3[n]) : 0.f;
  }
  if (FUSE) {
    for (int i = tid; i < 112; i += 256) {
      gs[i] = (i < DD) ? gemb[b * DD + i] : 0.f;
      os[i] = (i < DD) ? oemb[b * DD + i] : 0.f;
    }
  }
  for (int i = tid; i < 256 * H1S / 8; i += 256)
    ((uint4*)H1)[i] = make_uint4(0, 0, 0, 0);
  __syncthreads();

  // gather embeddings -> a1 fragments; fused NG write + origin-dot
  short8 a1[4][8];
  float pp[4] = {0.f, 0.f, 0.f, 0.f};
  #pragma unroll
  for (int mt = 0; mt < 4; ++mt) {
    const float* nrow = nemb + (size_t)nid[mt] * DD;
    const float* rrow = remb + (size_t)rid[mt] * DD;
    bool vrow = rowL[mt] < MKJ;
    #pragma unroll
    for (int ks = 0; ks < 8; ++ks) {
      const float* src = (ks < 4) ? nrow : rrow;
      int cb = (ks & 3) * 32 + lg * 8;
      float4 lo = make_float4(0.f,0.f,0.f,0.f), hi = lo;
      if (cb <= 96) lo = *(const float4*)(src + cb);
      if (cb + 4 <= 96) hi = *(const float4*)(src + cb + 4);
      union { short8 s; unsigned u[4]; } fr;
      fr.u[0] = pkbf2(lo.x, lo.y); fr.u[1] = pkbf2(lo.z, lo.w);
      fr.u[2] = pkbf2(hi.x, hi.y); fr.u[3] = pkbf2(hi.z, hi.w);
      a1[mt][ks] = fr.s;
      if (FUSE && ks < 4 && cb <= 96 && vrow) {
        float* ng = outNG + ((size_t)b * MKJ + rowL[mt]) * DD + cb;
        float4 t0;
        t0.x = lo.x + gs[cb+0]; t0.y = lo.y + gs[cb+1];
        t0.z = lo.z + gs[cb+2]; t0.w = lo.w + gs[cb+3];
        *(float4*)ng = t0;
        pp[mt] += os[cb+0]*t0.x + os[cb+1]*t0.y + os[cb+2]*t0.z + os[cb+3]*t0.w;
        if (cb + 4 <= 96) {
          float4 t1;
          t1.x = hi.x + gs[cb+4]; t1.y = hi.y + gs[cb+5];
          t1.z = hi.z + gs[cb+6]; t1.w = hi.w + gs[cb+7];
          *(float4*)(ng + 4) = t1;
          pp[mt] += os[cb+4]*t1.x + os[cb+5]*t1.y + os[cb+6]*t1.z + os[cb+7]*t1.w;
        }
      }
    }
  }
  if (FUSE) {
    #pragma unroll
    for (int mt = 0; mt < 4; ++mt) {
      float s = pp[mt];
      s += __shfl_xor(s, 16, 64);
      s += __shfl_xor(s, 32, 64);
      if (lg == mt && rowL[mt] < MKJ) dots[(size_t)b * MKJ + rowL[mt]] = s;
    }
  }

  float b3v[2] = {ab3[0], cb3[0]};
  float* outs[2] = {outA, outQ};

  for (int h = 0; h < 2; ++h) {
    // layer 1: C-init = G1, 8 ks MFMA x 4 m-tiles, tanh -> H1
    const short8* WF1h = (const short8*)wf1 + (size_t)h * (NT1 * K1S * 64);
    for (int nt = 0; nt < NT1; ++nt) {
      int n = nt * 16 + ln;
      float g = G1s[h * 112 + n];
      f32x4 acc[4];
      #pragma unroll
      for (int mt = 0; mt < 4; ++mt) { acc[mt][0]=g; acc[mt][1]=g; acc[mt][2]=g; acc[mt][3]=g; }
      #pragma unroll
      for (int ks = 0; ks < K1S; ++ks) {
        short8 bf = WF1h[(nt * K1S + ks) * 64 + lane];
        #pragma unroll
        for (int mt = 0; mt < 4; ++mt)
          acc[mt] = __builtin_amdgcn_mfma_f32_16x16x32_bf16(a1[mt][ks], bf, acc[mt], 0, 0, 0);
      }
      if (n < DD) {
        #pragma unroll
        for (int mt = 0; mt < 4; ++mt)
          #pragma unroll
          for (int r = 0; r < 4; ++r)
            H1[(w * 64 + mt * 16 + lg * 4 + r) * H1S + n] = f2bf(fast_tanh(acc[mt][r]));
      }
    }
    __syncthreads();

    // layer 2 + 3
    const short8* WF2h = (const short8*)wf2 + (size_t)h * (NT2 * K2S * 64);
    float part[4][4] = {};
    for (int nt = 0; nt < NT2; ++nt) {
      f32x4 acc[4];
      #pragma unroll
      for (int mt = 0; mt < 4; ++mt) { acc[mt][0]=0.f; acc[mt][1]=0.f; acc[mt][2]=0.f; acc[mt][3]=0.f; }
      #pragma unroll
      for (int ks = 0; ks < K2S; ++ks) {
        short8 bf = WF2h[(nt * K2S + ks) * 64 + lane];
        #pragma unroll
        for (int mt = 0; mt < 4; ++mt) {
          short8 a2 = *(const short8*)(H1 + (w * 64 + mt * 16 + ln) * H1S + ks * 32 + lg * 8);
          acc[mt] = __builtin_amdgcn_mfma_f32_16x16x32_bf16(a2, bf, acc[mt], 0, 0, 0);
        }
      }
      int n = nt * 16 + ln;
      float b2v = b2s[h * 112 + n];
      float w3v = w3s[h * 112 + n];
      #pragma unroll
      for (int mt = 0; mt < 4; ++mt)
        #pragma unroll
        for (int r = 0; r < 4; ++r)
          part[mt][r] += fast_tanh(acc[mt][r] + b2v) * w3v;
    }
    #pragma unroll
    for (int mt = 0; mt < 4; ++mt)
      #pragma unroll
      for (int r = 0; r < 4; ++r) {
        float s = part[mt][r];
        s += __shfl_xor(s, 1, 64); s += __shfl_xor(s, 2, 64);
        s += __shfl_xor(s, 4, 64); s += __shfl_xor(s, 8, 64);
        if (ln == 0) {
          int row = x * 256 + w * 64 + mt * 16 + lg * 4 + r;
          if (row < MKJ) outs[h][(size_t)b * MKJ + row] = fast_sigmoid(s + b3v[h]);
        }
      }
    __syncthreads();
  }
}

// ---------------- softmax over raw dots (in place in outDR) ----------------
__global__ __launch_bounds__(256) void k_soft(float* __restrict__ dr) {
  __shared__ float red[4];
  int b = blockIdx.x, tid = threadIdx.x;
  int lane = tid & 63, w = tid >> 6;
  float* p = dr + (size_t)b * MKJ;
  float v[4], mx = -1e30f;
  #pragma unroll
  for (int i = 0; i < 4; ++i) {
    int j = tid + i * 256;
    v[i] = (j < MKJ) ? p[j] : -1e30f;
    mx = fmaxf(mx, v[i]);
  }
  #pragma unroll
  for (int off = 32; off; off >>= 1) mx = fmaxf(mx, __shfl_xor(mx, off, 64));
  if (lane == 0) red[w] = mx;
  __syncthreads();
  mx = fmaxf(fmaxf(red[0], red[1]), fmaxf(red[2], red[3]));
  float e[4], se = 0.f;
  #pragma unroll
  for (int i = 0; i < 4; ++i) {
    e[i] = __expf(v[i] - mx);
    if (tid + i * 256 < MKJ) se += e[i];
  }
  #pragma unroll
  for (int off = 32; off; off >>= 1) se += __shfl_xor(se, off, 64);
  __syncthreads();
  if (lane == 0) red[w] = se;
  __syncthreads();
  se = red[0] + red[1] + red[2] + red[3];
  float inv = 1.f / se;
  #pragma unroll
  for (int i = 0; i < 4; ++i) {
    int j = tid + i * 256;
    if (j < MKJ) p[j] = e[i] * inv;
  }
}

// ---------------- fallback rewards (non-fused path) ----------------
__global__ __launch_bounds__(1024) void k_rewards(
    const float* __restrict__ nemb, const float* __restrict__ oemb,
    const float* __restrict__ gemb,
    const int* __restrict__ eadj, const int* __restrict__ nodes,
    float* __restrict__ outDR, float* __restrict__ outNG) {
  __shared__ float dots[MKJ];
  __shared__ float red[16];
  int b = blockIdx.x;
  int tid = threadIdx.x;
  int lane = tid & 63, w = tid >> 6;
  int d1 = lane + 64;
  float o0 = oemb[b * DD + lane];
  float g0 = gemb[b * DD + lane];
  float o1 = (d1 < DD) ? oemb[b * DD + d1] : 0.f;
  float g1 = (d1 < DD) ? gemb[b * DD + d1] : 0.f;
  for (int j = w; j < MKJ; j += 16) {
    int m = j / KADJ, kk = j - m * KADJ;
    int v = nodes[b * MM + m];
    int nid = eadj[v * KADJ + kk];
    const float* nr = nemb + (size_t)nid * DD;
    float s0 = g0 + nr[lane];
    float s1 = (d1 < DD) ? (g1 + nr[d1]) : 0.f;
    float* ngr = outNG + ((long long)b * MKJ + j) * DD;
    ngr[lane] = s0;
    if (d1 < DD) ngr[d1] = s1;
    float p = o0 * s0 + o1 * s1;
    p += __shfl_xor(p, 1, 64); p += __shfl_xor(p, 2, 64); p += __shfl_xor(p, 4, 64);
    p += __shfl_xor(p, 8, 64); p += __shfl_xor(p, 16, 64); p += __shfl_xor(p, 32, 64);
    if (lane == 0) dots[j] = p;
  }
  __syncthreads();
  float mx = -1e30f;
  for (int j = tid; j < MKJ; j += 1024) mx = fmaxf(mx, dots[j]);
  for (int off = 32; off; off >>= 1) mx = fmaxf(mx, __shfl_xor(mx, off, 64));
  if (lane == 0) red[w] = mx;
  __syncthreads();
  mx = red[0];
  #pragma unroll
  for (int i = 1; i < 16; ++i) mx = fmaxf(mx, red[i]);
  float se = 0.f;
  for (int j = tid; j < MKJ; j += 1024) se += __expf(dots[j] - mx);
  for (int off = 32; off; off >>= 1) se += __shfl_xor(se, off, 64);
  __syncthreads();
  if (lane == 0) red[w] = se;
  __syncthreads();
  se = 0.f;
  #pragma unroll
  for (int i = 0; i < 16; ++i) se += red[i];
  float inv = 1.f / se;
  for (int j = tid; j < MKJ; j += 1024) outDR[b * MKJ + j] = __expf(dots[j] - mx) * inv;
}

extern "C" void kernel_launch(void* const* d_in, const int* in_sizes, int n_in,
                              void* d_out, int out_size, void* d_ws, size_t ws_size,
                              hipStream_t stream) {
  const float* nemb = (const float*)d_in[0];
  const float* remb = (const float*)d_in[1];
  const float* oemb = (const float*)d_in[2];
  const float* gemb = (const float*)d_in[3];
  const float* aw1 = (const float*)d_in[4];
  const float* ab1 = (const float*)d_in[5];
  const float* aw2 = (const float*)d_in[6];
  const float* ab2 = (const float*)d_in[7];
  const float* aw3 = (const float*)d_in[8];
  const float* ab3 = (const float*)d_in[9];
  const float* cw1 = (const float*)d_in[10];
  const float* cb1 = (const float*)d_in[11];
  const float* cw2 = (const float*)d_in[12];
  const float* cb2 = (const float*)d_in[13];
  const float* cw3 = (const float*)d_in[14];
  const float* cb3 = (const float*)d_in[15];
  const int* eadj = (const int*)d_in[16];
  const int* radj = (const int*)d_in[17];
  const int* nodes = (const int*)d_in[18];

  float* out = (float*)d_out;
  float* outA = out;
  float* outQ = out + ROWS;
  float* outDR = out + 2 * ROWS;
  float* outNG = out + 3 * ROWS;

  // scratch: wf1 114,688 B | wf2 57,344 B | G1 212,992 B = 385,024 B
  const size_t need = 385024;
  bool fuse = ws_size >= need;
  char* scratch = (char*)d_ws;
  if (!fuse) {
    // fallback: tail of outNG (safe: non-fused k_heads never writes NG;
    // k_rewards overwrites it afterwards)
    scratch = (char*)(out + ((size_t)3 * ROWS + (size_t)ROWS * DD - need / 4));
  }
  short* wf1 = (short*)scratch;
  short* wf2 = (short*)(scratch + 114688);
  float* G1 = (float*)(scratch + 172032);

  k_prep<<<544, 256, 0, stream>>>(gemb, aw1, ab1, cw1, cb1, aw2, cw2, wf1, wf2, G1);
  dim3 hg(4, BB);
  if (fuse) {
    k_heads<true><<<hg, 256, 0, stream>>>(nemb, remb, oemb, gemb, eadj, radj, nodes,
                                          wf1, wf2, G1, ab2, cb2, aw3, ab3, cw3, cb3,
                                          outA, outQ, outDR, outNG);
    k_soft<<<BB, 256, 0, stream>>>(outDR);
  } else {
    k_heads<false><<<hg, 256, 0, stream>>>(nemb, remb, oemb, gemb, eadj, radj, nodes,
                                           wf1, wf2, G1, ab2, cb2, aw3, ab3, cw3, cb3,
                                           outA, outQ, outDR, outNG);
    k_rewards<<<BB, 1024, 0, stream>>>(nemb, oemb, gemb, eadj, nodes, outDR, outNG);
  }
}